// Round 6
// baseline (120.051 us; speedup 1.0000x reference)
//
#include <hip/hip_runtime.h>

// B=1, C=32, D=64, H=128, W=128. float32 in/out.
// Reverse scan along D: h = z[d]*_h[d] + (1-z[d])*h_prev, out[d] = h.
//
// R5 (resubmit — previous attempt died to an unresponsive container, no data):
// explicit 2-stage software pipeline. Prefetch chunk k+1's 16 loads while
// computing/storing chunk k. Named A/B buffers (static indexing only),
// sched_barrier(0) pins prefetch issue ahead of compute. nt stores kept from
// R4. __launch_bounds__(256,8): <=64 VGPR, holds 32 waves/CU.

#define GRU_C  32
#define GRU_D  64
#define GRU_HW (128 * 128)
#define CHUNK  8

#define LOAD_CHUNK(zb, hb, d0)                                   \
    _Pragma("unroll")                                            \
    for (int k = 0; k < CHUNK; ++k) {                            \
        const int idx = base + ((d0) + k) * GRU_HW;              \
        zb[k] = z[idx];                                          \
        hb[k] = h[idx];                                          \
    }

#define COMPUTE_STORE(zb, hb, d0)                                \
    _Pragma("unroll")                                            \
    for (int k = CHUNK - 1; k >= 0; --k) {                       \
        hp = fmaf(zb[k], hb[k], (1.0f - zb[k]) * hp);            \
        __builtin_nontemporal_store(hp, &out[base + ((d0) + k) * GRU_HW]); \
    }

__global__ __launch_bounds__(256, 8) void gru_rev_scan_kernel(
    const float* __restrict__ z,
    const float* __restrict__ h,
    const float* __restrict__ h0,
    float* __restrict__ out)
{
    const int tid = blockIdx.x * blockDim.x + threadIdx.x;  // 0 .. C*HW - 1
    const int c = tid >> 14;              // / 16384
    const int p = tid & (GRU_HW - 1);

    const int base = c * (GRU_D * GRU_HW) + p;

    float hp = h0[c * GRU_HW + p];

    float zA[CHUNK], hA[CHUNK], zB[CHUNK], hB[CHUNK];

    // prologue: chunk at d0=56 into A
    LOAD_CHUNK(zA, hA, GRU_D - CHUNK)
    __builtin_amdgcn_sched_barrier(0);

    // chunks: 56,48 / 40,32 / 24,16 in pipelined pairs; 8,0 in epilogue
    for (int d0 = GRU_D - CHUNK; d0 >= 24; d0 -= 2 * CHUNK) {
        LOAD_CHUNK(zB, hB, d0 - CHUNK)
        __builtin_amdgcn_sched_barrier(0);
        COMPUTE_STORE(zA, hA, d0)

        LOAD_CHUNK(zA, hA, d0 - 2 * CHUNK)
        __builtin_amdgcn_sched_barrier(0);
        COMPUTE_STORE(zB, hB, d0 - CHUNK)
    }

    // epilogue: A holds chunk d0=8; load chunk 0 into B, finish both
    LOAD_CHUNK(zB, hB, 0)
    __builtin_amdgcn_sched_barrier(0);
    COMPUTE_STORE(zA, hA, CHUNK)
    COMPUTE_STORE(zB, hB, 0)
}

extern "C" void kernel_launch(void* const* d_in, const int* in_sizes, int n_in,
                              void* d_out, int out_size, void* d_ws, size_t ws_size,
                              hipStream_t stream) {
    const float* z  = (const float*)d_in[0];
    const float* h  = (const float*)d_in[1];
    const float* h0 = (const float*)d_in[2];
    float* out = (float*)d_out;

    const int total_threads = GRU_C * GRU_HW;  // 524288
    const int block = 256;
    const int grid = total_threads / block;    // 2048

    gru_rev_scan_kernel<<<grid, block, 0, stream>>>(z, h, h0, out);
}

// Round 7
// 63.131 us; speedup vs baseline: 1.9016x; 1.9016x over previous
//
#include <hip/hip_runtime.h>

// B=1, C=32, D=64, H=128, W=128. float32 in/out.
// Reverse scan along D: h = z[d]*_h[d] + (1-z[d])*h_prev, out[d] = h.
//
// R6: R5's 2-stage pipeline but CHUNK=4 so it FITS IN REGISTERS.
// R5 post-mortem: CHUNK=8 double-buffer + 64-VGPR cap -> scratch spills
// (FETCH +117 MB, WRITE +82 MB). CHUNK=4: 2 bufs x 8 floats = 16 regs
// + addressing ~= 50 VGPR < 64. 8 loads in flight per wave during compute.
// nt stores kept from R4 (-21%).

#define GRU_C  32
#define GRU_D  64
#define GRU_HW (128 * 128)
#define CHUNK  4

#define LOAD_CHUNK(zb, hb, d0)                                   \
    _Pragma("unroll")                                            \
    for (int k = 0; k < CHUNK; ++k) {                            \
        const int idx = base + ((d0) + k) * GRU_HW;              \
        zb[k] = z[idx];                                          \
        hb[k] = h[idx];                                          \
    }

#define COMPUTE_STORE(zb, hb, d0)                                \
    _Pragma("unroll")                                            \
    for (int k = CHUNK - 1; k >= 0; --k) {                       \
        hp = fmaf(zb[k], hb[k], (1.0f - zb[k]) * hp);            \
        __builtin_nontemporal_store(hp, &out[base + ((d0) + k) * GRU_HW]); \
    }

__global__ __launch_bounds__(256, 8) void gru_rev_scan_kernel(
    const float* __restrict__ z,
    const float* __restrict__ h,
    const float* __restrict__ h0,
    float* __restrict__ out)
{
    const int tid = blockIdx.x * blockDim.x + threadIdx.x;  // 0 .. C*HW - 1
    const int c = tid >> 14;              // / 16384
    const int p = tid & (GRU_HW - 1);

    const int base = c * (GRU_D * GRU_HW) + p;

    float hp = h0[c * GRU_HW + p];

    float zA[CHUNK], hA[CHUNK], zB[CHUNK], hB[CHUNK];

    // prologue: chunk d0=60 into A
    LOAD_CHUNK(zA, hA, GRU_D - CHUNK)
    __builtin_amdgcn_sched_barrier(0);

    // each iteration handles chunks d0 and d0-4; A enters holding chunk d0
    for (int d0 = GRU_D - CHUNK; d0 >= 3 * CHUNK; d0 -= 2 * CHUNK) {
        LOAD_CHUNK(zB, hB, d0 - CHUNK)
        __builtin_amdgcn_sched_barrier(0);
        COMPUTE_STORE(zA, hA, d0)

        LOAD_CHUNK(zA, hA, d0 - 2 * CHUNK)
        __builtin_amdgcn_sched_barrier(0);
        COMPUTE_STORE(zB, hB, d0 - CHUNK)
    }

    // epilogue: A holds chunk d0=4; load chunk 0 into B, finish both
    LOAD_CHUNK(zB, hB, 0)
    __builtin_amdgcn_sched_barrier(0);
    COMPUTE_STORE(zA, hA, CHUNK)
    COMPUTE_STORE(zB, hB, 0)
}

extern "C" void kernel_launch(void* const* d_in, const int* in_sizes, int n_in,
                              void* d_out, int out_size, void* d_ws, size_t ws_size,
                              hipStream_t stream) {
    const float* z  = (const float*)d_in[0];
    const float* h  = (const float*)d_in[1];
    const float* h0 = (const float*)d_in[2];
    float* out = (float*)d_out;

    const int total_threads = GRU_C * GRU_HW;  // 524288
    const int block = 256;
    const int grid = total_threads / block;    // 2048

    gru_rev_scan_kernel<<<grid, block, 0, stream>>>(z, h, h0, out);
}